// Round 18
// baseline (562.785 us; speedup 1.0000x reference)
//
#include <hip/hip_runtime.h>
#include <hip/hip_bf16.h>

typedef __attribute__((ext_vector_type(8))) short short8;
typedef __attribute__((ext_vector_type(4))) float f32x4;

#define B_   2048
#define S_   67
#define M_   (B_*S_)     // 137216
#define HID_ 512
#define H_   8
#define KVH_ 4
#define D_   64

__device__ __forceinline__ unsigned f2bf_u(float f){
  union { __hip_bfloat16 h; unsigned short u; } c; c.h = __float2bfloat16(f); return (unsigned)c.u;
}
__device__ __forceinline__ float bfu2f(unsigned u){
  union { unsigned short u; __hip_bfloat16 h; } c; c.u = (unsigned short)u; return __bfloat162float(c.h);
}
__device__ __forceinline__ unsigned pack2(float a, float b){ return f2bf_u(a) | (f2bf_u(b) << 16); }

union S8 { short8 v; unsigned short u[8]; };

// ---------------- prep: merged weight transposes + x->bf16 convert (ONE launch) ------
__global__ __launch_bounds__(256) void prep_k(const float* __restrict__ x,
                                              const float* __restrict__ wq,
                                              const float* __restrict__ wk,
                                              const float* __restrict__ wv,
                                              const float* __restrict__ wo,
                                              unsigned short* __restrict__ xb,
                                              unsigned short* __restrict__ Wt,
                                              unsigned short* __restrict__ Wot){
  const int blk = blockIdx.x;
  if (blk < 768){
    __shared__ float tile[32][33];
    const float* src; unsigned short* dst; int ncols, row0, nb, kb;
    if (blk < 256)      { src = wq; dst = Wt;  ncols = 512; row0 = 0;
                          nb = (blk & 15)*32;        kb = (blk >> 4)*32; }
    else if (blk < 384) { int g = blk - 256; src = wk; dst = Wt; ncols = 256; row0 = 512;
                          nb = (g & 7)*32;           kb = (g >> 3)*32; }
    else if (blk < 512) { int g = blk - 384; src = wv; dst = Wt; ncols = 256; row0 = 768;
                          nb = (g & 7)*32;           kb = (g >> 3)*32; }
    else                { int g = blk - 512; src = wo; dst = Wot; ncols = 512; row0 = 0;
                          nb = (g & 15)*32;          kb = (g >> 4)*32; }
    const int tx = threadIdx.x & 31, ty = threadIdx.x >> 5;
    #pragma unroll
    for (int i = 0; i < 4; ++i){
      int r = ty + i*8;
      tile[r][tx] = src[(size_t)(kb + r)*ncols + nb + tx];
    }
    __syncthreads();
    #pragma unroll
    for (int i = 0; i < 4; ++i){
      int r = ty + i*8; // n within tile
      dst[(size_t)(row0 + nb + r)*512 + kb + tx] = (unsigned short)f2bf_u(tile[tx][r]);
    }
  } else {
    long i = (long)(blk - 768)*256 + threadIdx.x;
    const float4 a = reinterpret_cast<const float4*>(x)[2*i];
    const float4 b = reinterpret_cast<const float4*>(x)[2*i+1];
    uint4 u = { pack2(a.x,a.y), pack2(a.z,a.w), pack2(b.x,b.y), pack2(b.z,b.w) };
    reinterpret_cast<uint4*>(xb)[i] = u;
  }
}

// ---------------- bf16 MFMA GEMM v5: phased ring-4 pipeline --------------
// out[M][Nld] = A[M][512] @ Bw^T  (Bw is [Nld][512] bf16, k-contiguous)
// 256x256 tile, 8 waves, per-wave 128x64. BK=32, 16 K-tiles, ring of 4 LDS slots.
// NORM (QKV bf16 path only): RMSNorm applied during the LDS C-staging pass — thread t
// norms row t>>2, head t&3 (64 contiguous bf16 in Cs): no cross-lane ops. Q tiles
// (n0<512) scale by 1/||q||; K tile (n0==512) also by qnw*knw*0.125; V tile skipped.
// Norm is over bf16-rounded values = numerically identical to the in-attn original.
template<bool OUT_F32, bool NORM>
__global__ __launch_bounds__(512, 2) void gemm5_k(const unsigned short* __restrict__ A,
                                                  const unsigned short* __restrict__ Bw,
                                                  void* __restrict__ outp, int nbx,
                                                  const float* __restrict__ qnw,
                                                  const float* __restrict__ knw){
  __shared__ unsigned short Sh[4][2][256*32];   // [ring slot][A|B][256 rows x 32 k] = 128 KB
  __shared__ float ws[64];                      // K-head norm weights (NORM only)

  const int Nld = nbx << 8;
  const int per = gridDim.x >> 3;               // gridDim.x divisible by 8
  const int wg  = (blockIdx.x & 7) * per + (blockIdx.x >> 3);
  const int m0 = (wg / nbx) * 256;
  const int n0 = (wg % nbx) * 256;

  const int t = threadIdx.x;
  const int l = t & 63;
  const int w = t >> 6;                 // 0..7
  const int wr = w >> 2, wc = w & 3;    // wave tile: rows wr*128, cols wc*64
  const int lr = l & 15, lk = l >> 4;

  if (NORM && n0 == 512 && t < 64) ws[t] = qnw[t] * knw[t] * 0.125f;

  const int srow  = w*16 + (l >> 2);
  const int skblk = (l & 3) ^ ((l >> 2) & 3) ^ ((l >> 4) & 3);
  const unsigned short* Ag0 = A  + (size_t)(m0 + srow)*512 + skblk*8;
  const unsigned short* Bg0 = Bw + (size_t)(n0 + srow)*512 + skblk*8;

  const int pk = (lk ^ (lr & 3) ^ ((lr >> 2) & 3)) * 8;

  f32x4 acc[8][4];
  #pragma unroll
  for (int f = 0; f < 8; ++f)
    #pragma unroll
    for (int g = 0; g < 4; ++g) acc[f][g] = (f32x4){0.f, 0.f, 0.f, 0.f};

  short8 bv[4];   // B fragments for current K-tile (loaded at q0, reused at q1)

#define STAGE_OP_(op_, kt_) do{ \
    const unsigned short* src_ = ((op_) ? Bg0 : Ag0) + (size_t)(kt_)*32; \
    unsigned short* dst_ = &Sh[(kt_)&3][op_][(w*16)*32]; \
    __builtin_amdgcn_global_load_lds((const unsigned int*)src_, (unsigned int*)dst_, 16, 0, 0); \
    __builtin_amdgcn_global_load_lds((const unsigned int*)(src_ + (size_t)128*512), \
                                     (unsigned int*)(dst_ + 128*32), 16, 0, 0); \
  }while(0)

#define PHASE_(kt_, q_) do{ \
    const unsigned short* Asl = &Sh[(kt_)&3][0][0]; \
    const unsigned short* Bsl = &Sh[(kt_)&3][1][0]; \
    short8 av[4]; \
    _Pragma("unroll") \
    for (int f2 = 0; f2 < 4; ++f2) \
      av[f2] = *reinterpret_cast<const short8*>(Asl + (wr*128 + ((q_)*4 + f2)*16 + lr)*32 + pk); \
    if ((q_) == 0){ \
      _Pragma("unroll") \
      for (int g = 0; g < 4; ++g) \
        bv[g] = *reinterpret_cast<const short8*>(Bsl + (wc*64 + g*16 + lr)*32 + pk); \
    } \
    if ((kt_) + 2 <= 15) STAGE_OP_((q_), (kt_) + 2); \
    __builtin_amdgcn_s_barrier(); \
    asm volatile("s_waitcnt lgkmcnt(0)" ::: "memory"); \
    __builtin_amdgcn_sched_barrier(0); \
    __builtin_amdgcn_s_setprio(1); \
    _Pragma("unroll") \
    for (int f2 = 0; f2 < 4; ++f2) \
      _Pragma("unroll") \
      for (int g = 0; g < 4; ++g) \
        acc[(q_)*4 + f2][g] = __builtin_amdgcn_mfma_f32_16x16x32_bf16(av[f2], bv[g], acc[(q_)*4 + f2][g], 0, 0, 0); \
    __builtin_amdgcn_s_setprio(0); \
    if ((q_) == 1){ \
      if ((kt_) < 14)       { asm volatile("s_waitcnt vmcnt(4)" ::: "memory"); } \
      else if ((kt_) == 14) { asm volatile("s_waitcnt vmcnt(0)" ::: "memory"); } \
      __builtin_amdgcn_sched_barrier(0); \
    } \
    __builtin_amdgcn_s_barrier(); \
  }while(0)

  STAGE_OP_(0, 0); STAGE_OP_(1, 0); STAGE_OP_(0, 1); STAGE_OP_(1, 1);
  asm volatile("s_waitcnt vmcnt(4)" ::: "memory");
  __builtin_amdgcn_sched_barrier(0);
  __builtin_amdgcn_s_barrier();

  #pragma unroll
  for (int kt = 0; kt < 16; ++kt){
    PHASE_(kt, 0);
    PHASE_(kt, 1);
  }
#undef PHASE_
#undef STAGE_OP_

  if (OUT_F32){
    float* Cs = reinterpret_cast<float*>(&Sh[0][0][0]);
    float* out = (float*)outp;
    #pragma unroll
    for (int half = 0; half < 2; ++half){
      __syncthreads();
      if (wr == half){
        #pragma unroll
        for (int f = 0; f < 8; ++f)
          #pragma unroll
          for (int g = 0; g < 4; ++g)
            #pragma unroll
            for (int r = 0; r < 4; ++r){
              int row = f*16 + lk*4 + r;
              int col = wc*64 + g*16 + lr;
              Cs[row*256 + col] = acc[f][g][r];
            }
      }
      __syncthreads();
      const float4* Cv = reinterpret_cast<const float4*>(Cs);
      #pragma unroll
      for (int p = 0; p < 16; ++p){
        int idx = p*512 + t;
        int row = idx >> 6, c4 = idx & 63;
        *reinterpret_cast<float4*>(out + (size_t)(m0 + half*128 + row)*Nld + n0 + c4*4) = Cv[idx];
      }
    }
  } else {
    unsigned short* Cs = &Sh[0][0][0];
    unsigned short* out = (unsigned short*)outp;
    const bool doNorm = NORM && (n0 < 768);
    const bool isK    = NORM && (n0 == 512);
    #pragma unroll
    for (int half = 0; half < 2; ++half){
      __syncthreads();
      if (wr == half){
        #pragma unroll
        for (int f = 0; f < 8; ++f)
          #pragma unroll
          for (int g = 0; g < 4; ++g)
            #pragma unroll
            for (int r = 0; r < 4; ++r){
              int row = f*16 + lk*4 + r;
              int col = wc*64 + g*16 + lr;
              Cs[row*256 + col] = (unsigned short)f2bf_u(acc[f][g][r]);
            }
      }
      __syncthreads();
      if (doNorm){
        // thread t: row t>>2 (0..127 local), head t&3 -> 64 contiguous bf16 in Cs.
        unsigned short* rp = Cs + (t >> 2)*256 + (t & 3)*64;
        const int rot = t & 7;
        float ss = 0.f;
        #pragma unroll
        for (int j = 0; j < 8; ++j){
          int c = (j + rot) & 7;
          S8 a; a.v = *reinterpret_cast<const short8*>(rp + c*8);
          #pragma unroll
          for (int e = 0; e < 8; ++e){ float f = bfu2f(a.u[e]); ss += f*f; }
        }
        float inv = rsqrtf(ss*(1.0f/64.0f) + 1e-5f);
        #pragma unroll
        for (int j = 0; j < 8; ++j){
          int c = (j + rot) & 7;
          S8 a; a.v = *reinterpret_cast<const short8*>(rp + c*8);
          S8 o;
          #pragma unroll
          for (int e = 0; e < 8; ++e){
            float f = bfu2f(a.u[e]) * inv;
            if (isK) f *= ws[c*8 + e];
            o.u[e] = (unsigned short)f2bf_u(f);
          }
          *reinterpret_cast<short8*>(rp + c*8) = o.v;
        }
        __syncthreads();
      }
      const uint4* Cv = reinterpret_cast<const uint4*>(Cs);
      #pragma unroll
      for (int p = 0; p < 8; ++p){
        int idx = p*512 + t;
        int row = idx >> 5, c16 = idx & 31;
        *reinterpret_cast<uint4*>(out + (size_t)(m0 + half*128 + row)*Nld + n0 + c16*8) = Cv[idx];
      }
    }
  }
}

// ---------------- MFMA attention (norm pre-applied by QKV GEMM) --------------------
__global__ __launch_bounds__(576, 7) void attn_k(const unsigned short* __restrict__ qkv,
                                                 unsigned short* __restrict__ attn){
  __shared__ unsigned short Vt[64*104];          // 13 KB  V^T [d][s: 12 slots of 8]
  __shared__ unsigned short Kf[5][2][64*8];      // 10 KB  K fragments (MFMA reg layout)
  __shared__ unsigned short Pb[9][16*104];       // 29.25 KB per-wave P
  const int t = threadIdx.x;
  const int b = blockIdx.x >> 2, kvh = blockIdx.x & 3;
  const size_t rowbase = (size_t)b * 67;
  const int l = t & 63, w = t >> 6;
  const int lr = l & 15, lk = l >> 4;

  // ---------- issue global loads up front ----------
  const int vs = t >> 3, vd0 = (t & 7) << 3;
  uint4 vu = {0u,0u,0u,0u};
  if (vs < 67)
    vu = *reinterpret_cast<const uint4*>(qkv + (rowbase + vs)*1024 + 768 + kvh*64 + vd0);
  uint4 ku0 = {0u,0u,0u,0u}, ku1 = {0u,0u,0u,0u};
  if (w < 5){
    int s = w*16 + lr; if (s > 66) s = 66;
    const unsigned short* kp = qkv + (rowbase + s)*1024 + 512 + kvh*64 + lk*8;
    ku0 = *reinterpret_cast<const uint4*>(kp);
    ku1 = *reinterpret_cast<const uint4*>(kp + 32);
  }
  const int qrow = w*16 + lr;
  const int h01 = (qrow >= 67) ? 1 : 0;
  int qr = qrow - (h01 ? 67 : 0); if (qr > 66) qr = 66;
  const unsigned short* qp = qkv + (rowbase + qr)*1024 + (kvh*2 + h01)*64 + lk*8;
  const short8 qf0 = *reinterpret_cast<const short8*>(qp);
  const short8 qf1 = *reinterpret_cast<const short8*>(qp + 32);

  // ---------- stage V^T: row d (104 ushorts), slot = s>>3, phys = slot^((d>>3)&3) ----
  {
    unsigned short vsv[8];
    vsv[0]=vu.x&0xffffu; vsv[1]=vu.x>>16; vsv[2]=vu.y&0xffffu; vsv[3]=vu.y>>16;
    vsv[4]=vu.z&0xffffu; vsv[5]=vu.z>>16; vsv[6]=vu.w&0xffffu; vsv[7]=vu.w>>16;
    const int slot = vs >> 3;
    #pragma unroll
    for (int j = 0; j < 8; ++j){
      int d = vd0 + j;
      int phys = slot ^ ((d >> 3) & 3);
      Vt[d*104 + phys*8 + (vs & 7)] = vsv[j];    // zeros for vs >= 67
    }
    if (t < 192){                                 // zero pad s = 72..95 (slots 9..11)
      int s2 = 72 + (t >> 3);
      int slot2 = s2 >> 3;
      #pragma unroll
      for (int j = 0; j < 8; ++j){
        int d = vd0 + j;
        int phys = slot2 ^ ((d >> 3) & 3);
        Vt[d*104 + phys*8 + (s2 & 7)] = 0;
      }
    }
  }

  // ---------- K fragment nt = w (waves 0-4): raw copy to LDS (already normed) -------
  if (w < 5){
    *reinterpret_cast<uint4*>(&Kf[w][0][l*8]) = ku0;
    *reinterpret_cast<uint4*>(&Kf[w][1][l*8]) = ku1;
  }

  // ---------- zero my wave's Pb (16*104 ushorts = 208 uint4) ----------
  {
    uint4 z = {0u,0u,0u,0u};
    uint4* pz = reinterpret_cast<uint4*>(Pb[w]);
    for (int i = l; i < 208; i += 64) pz[i] = z;
  }
  __syncthreads();

  // ---------- QK^T ----------
  f32x4 sa[5];
  #pragma unroll
  for (int nt = 0; nt < 5; ++nt){
    short8 k0 = *reinterpret_cast<const short8*>(&Kf[nt][0][l*8]);
    short8 k1 = *reinterpret_cast<const short8*>(&Kf[nt][1][l*8]);
    sa[nt] = (f32x4){0.f,0.f,0.f,0.f};
    sa[nt] = __builtin_amdgcn_mfma_f32_16x16x32_bf16(qf0, k0, sa[nt], 0,0,0);
    sa[nt] = __builtin_amdgcn_mfma_f32_16x16x32_bf16(qf1, k1, sa[nt], 0,0,0);
  }

  // ---------- in-register softmax (divide deferred) ----------
  float inv4[4];
  #pragma unroll
  for (int r = 0; r < 4; ++r){
    float mx = -1e30f;
    #pragma unroll
    for (int nt = 0; nt < 5; ++nt){
      float v = sa[nt][r];
      if (nt*16 + lr >= 67) v = -1e30f;
      sa[nt][r] = v; mx = fmaxf(mx, v);
    }
    mx = fmaxf(mx, __shfl_xor(mx, 1));
    mx = fmaxf(mx, __shfl_xor(mx, 2));
    mx = fmaxf(mx, __shfl_xor(mx, 4));
    mx = fmaxf(mx, __shfl_xor(mx, 8));
    float sm = 0.f;
    #pragma unroll
    for (int nt = 0; nt < 5; ++nt){
      float e = __expf(sa[nt][r] - mx);
      sa[nt][r] = e; sm += e;
    }
    sm += __shfl_xor(sm, 1);
    sm += __shfl_xor(sm, 2);
    sm += __shfl_xor(sm, 4);
    sm += __shfl_xor(sm, 8);
    inv4[r] = 1.0f / sm;
  }

  // ---------- P (unnormalized e) -> LDS: slot = col>>3, phys = slot^((row>>3)&3) ----
  unsigned short* pb = Pb[w];
  #pragma unroll
  for (int nt = 0; nt < 5; ++nt)
    #pragma unroll
    for (int r = 0; r < 4; ++r){
      int row = lk*4 + r, col = nt*16 + lr;
      int phys = (col >> 3) ^ ((row >> 3) & 3);
      pb[row*104 + phys*8 + (col & 7)] = (unsigned short)f2bf_u(sa[nt][r]);
    }

  // ---------- PV ----------
  f32x4 oa[4];
  #pragma unroll
  for (int dt = 0; dt < 4; ++dt) oa[dt] = (f32x4){0.f,0.f,0.f,0.f};
  #pragma unroll
  for (int ks = 0; ks < 3; ++ks){
    int physp = (ks*4 + lk) ^ ((lr >> 3) & 3);
    short8 pf = *reinterpret_cast<const short8*>(&pb[lr*104 + physp*8]);
    #pragma unroll
    for (int dt = 0; dt < 4; ++dt){
      int d = dt*16 + lr;
      int physv = (ks*4 + lk) ^ ((d >> 3) & 3);
      short8 vf = *reinterpret_cast<const short8*>(&Vt[d*104 + physv*8]);
      oa[dt] = __builtin_amdgcn_mfma_f32_16x16x32_bf16(pf, vf, oa[dt], 0,0,0);
    }
  }

  // ---------- O epilogue: apply 1/sum, write ----------
  #pragma unroll
  for (int dt = 0; dt < 4; ++dt)
    #pragma unroll
    for (int r = 0; r < 4; ++r){
      int row = w*16 + lk*4 + r;
      if (row < 134){
        int hh = (row >= 67) ? 1 : 0;
        int orow = row - (hh ? 67 : 0);
        attn[(rowbase + orow)*512 + (kvh*2 + hh)*64 + dt*16 + lr] =
            (unsigned short)f2bf_u(oa[dt][r] * inv4[r]);
      }
    }
}

extern "C" void kernel_launch(void* const* d_in, const int* in_sizes, int n_in,
                              void* d_out, int out_size, void* d_ws, size_t ws_size,
                              hipStream_t stream){
  const float* x   = (const float*)d_in[0];
  const float* wq  = (const float*)d_in[1];
  const float* wk  = (const float*)d_in[2];
  const float* wv  = (const float*)d_in[3];
  const float* wo  = (const float*)d_in[4];
  const float* qnw = (const float*)d_in[5];
  const float* knw = (const float*)d_in[6];

  unsigned short* Wt   = (unsigned short*)d_ws;          // [1024][512] bf16
  unsigned short* Wot  = Wt + 1024*512;                  // [512][512] bf16
  unsigned short* qkv  = Wot + 512*512;                  // [M][1024] bf16 (Q,K normed)
  unsigned short* attn = qkv + (size_t)M_*1024;          // [M][512] bf16
  unsigned short* xb   = attn;                           // alias: xb dead before attn written

  // merged prep: 4 weight transposes (768 blocks) + x->bf16
  prep_k<<<dim3(768 + M_*512/8/256), 256, 0, stream>>>(x, wq, wk, wv, wo, xb, Wt, Wot);

  // QKV projection + fused RMSNorm (LDS-pass, shuffle-free): [M][512] bf16 -> [M][1024] bf16
  gemm5_k<false,true><<<dim3(4 * (M_/256)), 512, 0, stream>>>(xb, Wt, qkv, 4, qnw, knw);

  // attention (MFMA, norm-free)
  attn_k<<<dim3(B_*KVH_), 576, 0, stream>>>(qkv, attn);

  // output projection: [M][512] bf16 @ -> [M][512] fp32
  gemm5_k<true,false><<<dim3(2 * (M_/256)), 512, 0, stream>>>(attn, Wot, d_out, 2, nullptr, nullptr);
}

// Round 19
// 514.250 us; speedup vs baseline: 1.0944x; 1.0944x over previous
//
#include <hip/hip_runtime.h>
#include <hip/hip_bf16.h>

typedef __attribute__((ext_vector_type(8))) short short8;
typedef __attribute__((ext_vector_type(4))) float f32x4;

#define B_   2048
#define S_   67
#define M_   (B_*S_)     // 137216
#define HID_ 512
#define H_   8
#define KVH_ 4
#define D_   64

__device__ __forceinline__ unsigned f2bf_u(float f){
  union { __hip_bfloat16 h; unsigned short u; } c; c.h = __float2bfloat16(f); return (unsigned)c.u;
}
__device__ __forceinline__ float bfu2f(unsigned u){
  union { unsigned short u; __hip_bfloat16 h; } c; c.u = (unsigned short)u; return __bfloat162float(c.h);
}
__device__ __forceinline__ unsigned pack2(float a, float b){ return f2bf_u(a) | (f2bf_u(b) << 16); }

__device__ __forceinline__ void unpack8(uint4 v, float* o){
  o[0]=bfu2f(v.x & 0xffffu); o[1]=bfu2f(v.x >> 16);
  o[2]=bfu2f(v.y & 0xffffu); o[3]=bfu2f(v.y >> 16);
  o[4]=bfu2f(v.z & 0xffffu); o[5]=bfu2f(v.z >> 16);
  o[6]=bfu2f(v.w & 0xffffu); o[7]=bfu2f(v.w >> 16);
}

union S8 { short8 v; unsigned short u[8]; };

// ---------------- prep: merged weight transposes + x->bf16 convert (ONE launch) ------
__global__ __launch_bounds__(256) void prep_k(const float* __restrict__ x,
                                              const float* __restrict__ wq,
                                              const float* __restrict__ wk,
                                              const float* __restrict__ wv,
                                              const float* __restrict__ wo,
                                              unsigned short* __restrict__ xb,
                                              unsigned short* __restrict__ Wt,
                                              unsigned short* __restrict__ Wot){
  const int blk = blockIdx.x;
  if (blk < 768){
    __shared__ float tile[32][33];
    const float* src; unsigned short* dst; int ncols, row0, nb, kb;
    if (blk < 256)      { src = wq; dst = Wt;  ncols = 512; row0 = 0;
                          nb = (blk & 15)*32;        kb = (blk >> 4)*32; }
    else if (blk < 384) { int g = blk - 256; src = wk; dst = Wt; ncols = 256; row0 = 512;
                          nb = (g & 7)*32;           kb = (g >> 3)*32; }
    else if (blk < 512) { int g = blk - 384; src = wv; dst = Wt; ncols = 256; row0 = 768;
                          nb = (g & 7)*32;           kb = (g >> 3)*32; }
    else                { int g = blk - 512; src = wo; dst = Wot; ncols = 512; row0 = 0;
                          nb = (g & 15)*32;          kb = (g >> 4)*32; }
    const int tx = threadIdx.x & 31, ty = threadIdx.x >> 5;
    #pragma unroll
    for (int i = 0; i < 4; ++i){
      int r = ty + i*8;
      tile[r][tx] = src[(size_t)(kb + r)*ncols + nb + tx];
    }
    __syncthreads();
    #pragma unroll
    for (int i = 0; i < 4; ++i){
      int r = ty + i*8; // n within tile
      dst[(size_t)(row0 + nb + r)*512 + kb + tx] = (unsigned short)f2bf_u(tile[tx][r]);
    }
  } else {
    long i = (long)(blk - 768)*256 + threadIdx.x;
    const float4 a = reinterpret_cast<const float4*>(x)[2*i];
    const float4 b = reinterpret_cast<const float4*>(x)[2*i+1];
    uint4 u = { pack2(a.x,a.y), pack2(a.z,a.w), pack2(b.x,b.y), pack2(b.z,b.w) };
    reinterpret_cast<uint4*>(xb)[i] = u;
  }
}

// ---------------- bf16 MFMA GEMM v5: phased ring-4 pipeline --------------
// out[M][Nld] = A[M][512] @ Bw^T  (Bw is [Nld][512] bf16, k-contiguous)
// 256x256 tile, 8 waves, per-wave 128x64. BK=32, 16 K-tiles, ring of 4 LDS slots.
template<bool OUT_F32>
__global__ __launch_bounds__(512, 2) void gemm5_k(const unsigned short* __restrict__ A,
                                                  const unsigned short* __restrict__ Bw,
                                                  void* __restrict__ outp, int nbx){
  __shared__ unsigned short Sh[4][2][256*32];   // [ring slot][A|B][256 rows x 32 k] = 128 KB

  const int Nld = nbx << 8;
  const int per = gridDim.x >> 3;               // gridDim.x divisible by 8
  const int wg  = (blockIdx.x & 7) * per + (blockIdx.x >> 3);
  const int m0 = (wg / nbx) * 256;
  const int n0 = (wg % nbx) * 256;

  const int t = threadIdx.x;
  const int l = t & 63;
  const int w = t >> 6;                 // 0..7
  const int wr = w >> 2, wc = w & 3;    // wave tile: rows wr*128, cols wc*64
  const int lr = l & 15, lk = l >> 4;

  const int srow  = w*16 + (l >> 2);
  const int skblk = (l & 3) ^ ((l >> 2) & 3) ^ ((l >> 4) & 3);
  const unsigned short* Ag0 = A  + (size_t)(m0 + srow)*512 + skblk*8;
  const unsigned short* Bg0 = Bw + (size_t)(n0 + srow)*512 + skblk*8;

  const int pk = (lk ^ (lr & 3) ^ ((lr >> 2) & 3)) * 8;

  f32x4 acc[8][4];
  #pragma unroll
  for (int f = 0; f < 8; ++f)
    #pragma unroll
    for (int g = 0; g < 4; ++g) acc[f][g] = (f32x4){0.f, 0.f, 0.f, 0.f};

  short8 bv[4];   // B fragments for current K-tile (loaded at q0, reused at q1)

#define STAGE_OP_(op_, kt_) do{ \
    const unsigned short* src_ = ((op_) ? Bg0 : Ag0) + (size_t)(kt_)*32; \
    unsigned short* dst_ = &Sh[(kt_)&3][op_][(w*16)*32]; \
    __builtin_amdgcn_global_load_lds((const unsigned int*)src_, (unsigned int*)dst_, 16, 0, 0); \
    __builtin_amdgcn_global_load_lds((const unsigned int*)(src_ + (size_t)128*512), \
                                     (unsigned int*)(dst_ + 128*32), 16, 0, 0); \
  }while(0)

#define PHASE_(kt_, q_) do{ \
    const unsigned short* Asl = &Sh[(kt_)&3][0][0]; \
    const unsigned short* Bsl = &Sh[(kt_)&3][1][0]; \
    short8 av[4]; \
    _Pragma("unroll") \
    for (int f2 = 0; f2 < 4; ++f2) \
      av[f2] = *reinterpret_cast<const short8*>(Asl + (wr*128 + ((q_)*4 + f2)*16 + lr)*32 + pk); \
    if ((q_) == 0){ \
      _Pragma("unroll") \
      for (int g = 0; g < 4; ++g) \
        bv[g] = *reinterpret_cast<const short8*>(Bsl + (wc*64 + g*16 + lr)*32 + pk); \
    } \
    if ((kt_) + 2 <= 15) STAGE_OP_((q_), (kt_) + 2); \
    __builtin_amdgcn_s_barrier(); \
    asm volatile("s_waitcnt lgkmcnt(0)" ::: "memory"); \
    __builtin_amdgcn_sched_barrier(0); \
    __builtin_amdgcn_s_setprio(1); \
    _Pragma("unroll") \
    for (int f2 = 0; f2 < 4; ++f2) \
      _Pragma("unroll") \
      for (int g = 0; g < 4; ++g) \
        acc[(q_)*4 + f2][g] = __builtin_amdgcn_mfma_f32_16x16x32_bf16(av[f2], bv[g], acc[(q_)*4 + f2][g], 0, 0, 0); \
    __builtin_amdgcn_s_setprio(0); \
    if ((q_) == 1){ \
      if ((kt_) < 14)       { asm volatile("s_waitcnt vmcnt(4)" ::: "memory"); } \
      else if ((kt_) == 14) { asm volatile("s_waitcnt vmcnt(0)" ::: "memory"); } \
      __builtin_amdgcn_sched_barrier(0); \
    } \
    __builtin_amdgcn_s_barrier(); \
  }while(0)

  STAGE_OP_(0, 0); STAGE_OP_(1, 0); STAGE_OP_(0, 1); STAGE_OP_(1, 1);
  asm volatile("s_waitcnt vmcnt(4)" ::: "memory");
  __builtin_amdgcn_sched_barrier(0);
  __builtin_amdgcn_s_barrier();

  #pragma unroll
  for (int kt = 0; kt < 16; ++kt){
    PHASE_(kt, 0);
    PHASE_(kt, 1);
  }
#undef PHASE_
#undef STAGE_OP_

  if (OUT_F32){
    float* Cs = reinterpret_cast<float*>(&Sh[0][0][0]);
    float* out = (float*)outp;
    #pragma unroll
    for (int half = 0; half < 2; ++half){
      __syncthreads();
      if (wr == half){
        #pragma unroll
        for (int f = 0; f < 8; ++f)
          #pragma unroll
          for (int g = 0; g < 4; ++g)
            #pragma unroll
            for (int r = 0; r < 4; ++r){
              int row = f*16 + lk*4 + r;
              int col = wc*64 + g*16 + lr;
              Cs[row*256 + col] = acc[f][g][r];
            }
      }
      __syncthreads();
      const float4* Cv = reinterpret_cast<const float4*>(Cs);
      #pragma unroll
      for (int p = 0; p < 16; ++p){
        int idx = p*512 + t;
        int row = idx >> 6, c4 = idx & 63;
        *reinterpret_cast<float4*>(out + (size_t)(m0 + half*128 + row)*Nld + n0 + c4*4) = Cv[idx];
      }
    }
  } else {
    unsigned short* Cs = &Sh[0][0][0];
    unsigned short* out = (unsigned short*)outp;
    #pragma unroll
    for (int half = 0; half < 2; ++half){
      __syncthreads();
      if (wr == half){
        #pragma unroll
        for (int f = 0; f < 8; ++f)
          #pragma unroll
          for (int g = 0; g < 4; ++g)
            #pragma unroll
            for (int r = 0; r < 4; ++r){
              int row = f*16 + lk*4 + r;
              int col = wc*64 + g*16 + lr;
              Cs[row*256 + col] = (unsigned short)f2bf_u(acc[f][g][r]);
            }
      }
      __syncthreads();
      const uint4* Cv = reinterpret_cast<const uint4*>(Cs);
      #pragma unroll
      for (int p = 0; p < 8; ++p){
        int idx = p*512 + t;
        int row = idx >> 5, c16 = idx & 31;
        *reinterpret_cast<uint4*>(out + (size_t)(m0 + half*128 + row)*Nld + n0 + c16*8) = Cv[idx];
      }
    }
  }
}

// ---------------- MFMA attention: one block per (b,kvh), 9 waves, 1 strip/wave ----
// LDS re-laid to 104-col (13-slot) rows for Vt/Pb: 208 B row stride rotates bank base
// (20*row mod 32), so b128 reads are ~2-way; slot^((row>>3)&3) spreads scalar writes.
// Total LDS 52.3 KB -> 3 blocks/CU; __launch_bounds__(576,7) caps VGPR for 27 waves/CU.
__global__ __launch_bounds__(576, 7) void attn_k(const unsigned short* __restrict__ qkv,
                                                 const float* __restrict__ qnw,
                                                 const float* __restrict__ knw,
                                                 unsigned short* __restrict__ attn){
  __shared__ unsigned short Vt[64*104];          // 13 KB  V^T [d][s: 12 slots of 8]
  __shared__ unsigned short Kf[5][2][64*8];      // 10 KB  K fragments (MFMA reg layout)
  __shared__ unsigned short Pb[9][16*104];       // 29.25 KB per-wave P
  const int t = threadIdx.x;
  const int b = blockIdx.x >> 2, kvh = blockIdx.x & 3;
  const size_t rowbase = (size_t)b * 67;
  const int l = t & 63, w = t >> 6;
  const int lr = l & 15, lk = l >> 4;

  // ---------- issue global loads up front ----------
  const int vs = t >> 3, vd0 = (t & 7) << 3;
  uint4 vu = {0u,0u,0u,0u};
  if (vs < 67)
    vu = *reinterpret_cast<const uint4*>(qkv + (rowbase + vs)*1024 + 768 + kvh*64 + vd0);
  uint4 ku0 = {0u,0u,0u,0u}, ku1 = {0u,0u,0u,0u};
  if (w < 5){
    int s = w*16 + lr; if (s > 66) s = 66;
    const unsigned short* kp = qkv + (rowbase + s)*1024 + 512 + kvh*64 + lk*8;
    ku0 = *reinterpret_cast<const uint4*>(kp);
    ku1 = *reinterpret_cast<const uint4*>(kp + 32);
  }
  const int qrow = w*16 + lr;
  const int h01 = (qrow >= 67) ? 1 : 0;
  int qr = qrow - (h01 ? 67 : 0); if (qr > 66) qr = 66;
  const unsigned short* qp = qkv + (rowbase + qr)*1024 + (kvh*2 + h01)*64 + lk*8;
  const uint4 qu0 = *reinterpret_cast<const uint4*>(qp);
  const uint4 qu1 = *reinterpret_cast<const uint4*>(qp + 32);

  // ---------- stage V^T: row d (104 ushorts), slot = s>>3, phys = slot^((d>>3)&3) ----
  {
    unsigned short vsv[8];
    vsv[0]=vu.x&0xffffu; vsv[1]=vu.x>>16; vsv[2]=vu.y&0xffffu; vsv[3]=vu.y>>16;
    vsv[4]=vu.z&0xffffu; vsv[5]=vu.z>>16; vsv[6]=vu.w&0xffffu; vsv[7]=vu.w>>16;
    const int slot = vs >> 3;
    #pragma unroll
    for (int j = 0; j < 8; ++j){
      int d = vd0 + j;
      int phys = slot ^ ((d >> 3) & 3);
      Vt[d*104 + phys*8 + (vs & 7)] = vsv[j];    // zeros for vs >= 67
    }
    if (t < 192){                                 // zero pad s = 72..95 (slots 9..11)
      int s2 = 72 + (t >> 3);
      int slot2 = s2 >> 3;
      #pragma unroll
      for (int j = 0; j < 8; ++j){
        int d = vd0 + j;
        int phys = slot2 ^ ((d >> 3) & 3);
        Vt[d*104 + phys*8 + (s2 & 7)] = 0;
      }
    }
  }

  // ---------- K fragment nt = w (waves 0-4): norm + weight, share via LDS ----------
  if (w < 5){
    float wp[16];
    #pragma unroll
    for (int hh = 0; hh < 2; ++hh)
      #pragma unroll
      for (int j = 0; j < 8; ++j){
        int idx = hh*32 + lk*8 + j;
        wp[hh*8+j] = qnw[idx] * knw[idx] * 0.125f;
      }
    float f[16]; unpack8(ku0, f); unpack8(ku1, f + 8);
    float ss = 0.f;
    #pragma unroll
    for (int j = 0; j < 16; ++j) ss += f[j]*f[j];
    ss += __shfl_xor(ss, 16); ss += __shfl_xor(ss, 32);
    float inv = rsqrtf(ss*(1.0f/64.0f) + 1e-5f);
    S8 a0, a1;
    #pragma unroll
    for (int j = 0; j < 8; ++j){
      a0.u[j] = (unsigned short)f2bf_u(f[j]   * inv * wp[j]);
      a1.u[j] = (unsigned short)f2bf_u(f[8+j] * inv * wp[8+j]);
    }
    *reinterpret_cast<short8*>(&Kf[w][0][l*8]) = a0.v;
    *reinterpret_cast<short8*>(&Kf[w][1][l*8]) = a1.v;
  }

  // ---------- Q fragments, normed (weights folded into K) ----------
  short8 qf0, qf1;
  {
    float f[16]; unpack8(qu0, f); unpack8(qu1, f + 8);
    float ss = 0.f;
    #pragma unroll
    for (int j = 0; j < 16; ++j) ss += f[j]*f[j];
    ss += __shfl_xor(ss, 16); ss += __shfl_xor(ss, 32);
    float inv = rsqrtf(ss*(1.0f/64.0f) + 1e-5f);
    S8 a0, a1;
    #pragma unroll
    for (int j = 0; j < 8; ++j){
      a0.u[j] = (unsigned short)f2bf_u(f[j]   * inv);
      a1.u[j] = (unsigned short)f2bf_u(f[8+j] * inv);
    }
    qf0 = a0.v; qf1 = a1.v;
  }

  // ---------- zero my wave's Pb (16*104 ushorts = 208 uint4) ----------
  {
    uint4 z = {0u,0u,0u,0u};
    uint4* pz = reinterpret_cast<uint4*>(Pb[w]);
    for (int i = l; i < 208; i += 64) pz[i] = z;
  }
  __syncthreads();

  // ---------- QK^T ----------
  f32x4 sa[5];
  #pragma unroll
  for (int nt = 0; nt < 5; ++nt){
    short8 k0 = *reinterpret_cast<const short8*>(&Kf[nt][0][l*8]);
    short8 k1 = *reinterpret_cast<const short8*>(&Kf[nt][1][l*8]);
    sa[nt] = (f32x4){0.f,0.f,0.f,0.f};
    sa[nt] = __builtin_amdgcn_mfma_f32_16x16x32_bf16(qf0, k0, sa[nt], 0,0,0);
    sa[nt] = __builtin_amdgcn_mfma_f32_16x16x32_bf16(qf1, k1, sa[nt], 0,0,0);
  }

  // ---------- in-register softmax (divide deferred) ----------
  float inv4[4];
  #pragma unroll
  for (int r = 0; r < 4; ++r){
    float mx = -1e30f;
    #pragma unroll
    for (int nt = 0; nt < 5; ++nt){
      float v = sa[nt][r];
      if (nt*16 + lr >= 67) v = -1e30f;
      sa[nt][r] = v; mx = fmaxf(mx, v);
    }
    mx = fmaxf(mx, __shfl_xor(mx, 1));
    mx = fmaxf(mx, __shfl_xor(mx, 2));
    mx = fmaxf(mx, __shfl_xor(mx, 4));
    mx = fmaxf(mx, __shfl_xor(mx, 8));
    float sm = 0.f;
    #pragma unroll
    for (int nt = 0; nt < 5; ++nt){
      float e = __expf(sa[nt][r] - mx);
      sa[nt][r] = e; sm += e;
    }
    sm += __shfl_xor(sm, 1);
    sm += __shfl_xor(sm, 2);
    sm += __shfl_xor(sm, 4);
    sm += __shfl_xor(sm, 8);
    inv4[r] = 1.0f / sm;
  }

  // ---------- P (unnormalized e) -> LDS: slot = col>>3, phys = slot^((row>>3)&3) ----
  unsigned short* pb = Pb[w];
  #pragma unroll
  for (int nt = 0; nt < 5; ++nt)
    #pragma unroll
    for (int r = 0; r < 4; ++r){
      int row = lk*4 + r, col = nt*16 + lr;
      int phys = (col >> 3) ^ ((row >> 3) & 3);
      pb[row*104 + phys*8 + (col & 7)] = (unsigned short)f2bf_u(sa[nt][r]);
    }

  // ---------- PV ----------
  f32x4 oa[4];
  #pragma unroll
  for (int dt = 0; dt < 4; ++dt) oa[dt] = (f32x4){0.f,0.f,0.f,0.f};
  #pragma unroll
  for (int ks = 0; ks < 3; ++ks){
    int physp = (ks*4 + lk) ^ ((lr >> 3) & 3);
    short8 pf = *reinterpret_cast<const short8*>(&pb[lr*104 + physp*8]);
    #pragma unroll
    for (int dt = 0; dt < 4; ++dt){
      int d = dt*16 + lr;
      int physv = (ks*4 + lk) ^ ((d >> 3) & 3);
      short8 vf = *reinterpret_cast<const short8*>(&Vt[d*104 + physv*8]);
      oa[dt] = __builtin_amdgcn_mfma_f32_16x16x32_bf16(pf, vf, oa[dt], 0,0,0);
    }
  }

  // ---------- O epilogue: apply 1/sum, write ----------
  #pragma unroll
  for (int dt = 0; dt < 4; ++dt)
    #pragma unroll
    for (int r = 0; r < 4; ++r){
      int row = w*16 + lk*4 + r;
      if (row < 134){
        int hh = (row >= 67) ? 1 : 0;
        int orow = row - (hh ? 67 : 0);
        attn[(rowbase + orow)*512 + (kvh*2 + hh)*64 + dt*16 + lr] =
            (unsigned short)f2bf_u(oa[dt][r] * inv4[r]);
      }
    }
}

extern "C" void kernel_launch(void* const* d_in, const int* in_sizes, int n_in,
                              void* d_out, int out_size, void* d_ws, size_t ws_size,
                              hipStream_t stream){
  const float* x   = (const float*)d_in[0];
  const float* wq  = (const float*)d_in[1];
  const float* wk  = (const float*)d_in[2];
  const float* wv  = (const float*)d_in[3];
  const float* wo  = (const float*)d_in[4];
  const float* qnw = (const float*)d_in[5];
  const float* knw = (const float*)d_in[6];

  unsigned short* Wt   = (unsigned short*)d_ws;          // [1024][512] bf16
  unsigned short* Wot  = Wt + 1024*512;                  // [512][512] bf16
  unsigned short* qkv  = Wot + 512*512;                  // [M][1024] bf16
  unsigned short* attn = qkv + (size_t)M_*1024;          // [M][512] bf16
  unsigned short* xb   = attn;                           // alias: xb dead before attn written

  // merged prep: 4 weight transposes (768 blocks) + x->bf16 (34304 blocks)
  prep_k<<<dim3(768 + M_*512/8/256), 256, 0, stream>>>(x, wq, wk, wv, wo, xb, Wt, Wot);

  // QKV projection: [M][512] bf16 @ -> [M][1024] bf16  (536*4 = 2144 blocks, /8 ok)
  gemm5_k<false><<<dim3(4 * (M_/256)), 512, 0, stream>>>(xb, Wt, qkv, 4);

  // attention (MFMA, single-pass, K-norm dedup, 3 blocks/CU layout)
  attn_k<<<dim3(B_*KVH_), 576, 0, stream>>>(qkv, qnw, knw, attn);

  // output projection: [M][512] bf16 @ -> [M][512] fp32 (536*2 = 1072 blocks, /8 ok)
  gemm5_k<true><<<dim3(2 * (M_/256)), 512, 0, stream>>>(attn, Wot, d_out, 2);
}